// Round 1
// baseline (378.584 us; speedup 1.0000x reference)
//
#include <hip/hip_runtime.h>

// ============================================================================
// ExtraMHSA fused pipeline for MI355X (gfx950).
//
// Stages (all bf16 MFMA 16x16x32, fp32 accumulate):
//   prep_weights : fold BN scale into conv weights, concat proj weights, ->bf16
//   prep_xT      : x [256][6400] fp32 -> xT [6400][256] bf16 (A-side layout)
//   prep_pos     : cp=rel_h+rel_w -> LT[:,128:256]; ef -> efT (j-major) + efc (c-major)
//   gemm_x1      : x1T = silu(conv1(x))             [6400][128] bf16
//   gemm_qkvp    : q,k,v,p -> LT/RT/V/pT layouts
//   attn_kernel  : S=exp(L^T R) (NO max subtraction - scores bounded ~26),
//                  O += P*V^T, l += rowsum(P); per-jp partial outputs
//   combine_k    : out?T[i][c] = sum_p O_p / sum_p l_p  -> bf16
//   final_k      : out = x + silu(bn(conv2(out1))) + silu(bn(conv3(out2)))
// ============================================================================

typedef unsigned short u16;
typedef __attribute__((ext_vector_type(8))) short bf16x8;   // 8 bf16 = 4 VGPRs
typedef __attribute__((ext_vector_type(4))) float f32x4;    // MFMA C/D frag
typedef __attribute__((ext_vector_type(4))) unsigned int u32x4;

#define HW 6400
#define BN_EPS 1e-5f

__device__ __forceinline__ u16 f2b(float f) {       // fp32 -> bf16 RNE
  unsigned u = __float_as_uint(f);
  u += 0x7fffu + ((u >> 16) & 1u);
  return (u16)(u >> 16);
}
__device__ __forceinline__ unsigned pack2(float a, float b) {
  return (unsigned)f2b(a) | ((unsigned)f2b(b) << 16);
}
__device__ __forceinline__ f32x4 MFMA(bf16x8 a, bf16x8 b, f32x4 c) {
  return __builtin_amdgcn_mfma_f32_16x16x32_bf16(a, b, c, 0, 0, 0);
}
__device__ __forceinline__ float silu_f(float y) {
  return y / (1.0f + __expf(-y));
}

// ---------------------------------------------------------------------------
// prep_weights: BN fold + bf16 conversion. grid <<<64,256>>>
// ---------------------------------------------------------------------------
__global__ void prep_weights(
    const float* __restrict__ w1, const float* __restrict__ g1, const float* __restrict__ b1,
    const float* __restrict__ m1, const float* __restrict__ v1,
    const float* __restrict__ w2, const float* __restrict__ g2, const float* __restrict__ b2,
    const float* __restrict__ m2, const float* __restrict__ v2,
    const float* __restrict__ w3, const float* __restrict__ g3, const float* __restrict__ b3,
    const float* __restrict__ m3, const float* __restrict__ v3,
    const float* __restrict__ wq, const float* __restrict__ bq,
    const float* __restrict__ wk, const float* __restrict__ bk,
    const float* __restrict__ wv, const float* __restrict__ bv,
    const float* __restrict__ wp, const float* __restrict__ bp,
    u16* __restrict__ w1b, float* __restrict__ b1e,
    u16* __restrict__ Wcat, float* __restrict__ bcat,
    u16* __restrict__ w2b, float* __restrict__ b2e,
    u16* __restrict__ w3b, float* __restrict__ b3e)
{
  const int tid = blockIdx.x * 256 + threadIdx.x;
  const int stride = gridDim.x * 256;
  for (int idx = tid; idx < 128 * 256; idx += stride) {
    int o = idx >> 8;
    float s = g1[o] * rsqrtf(v1[o] + BN_EPS);
    w1b[idx] = f2b(w1[idx] * s);
  }
  for (int idx = tid; idx < 128; idx += stride) {
    float s = g1[idx] * rsqrtf(v1[idx] + BN_EPS);
    b1e[idx] = b1[idx] - m1[idx] * s;
  }
  for (int idx = tid; idx < 4 * 128 * 128; idx += stride) {
    int which = idx >> 14, r = idx & 16383;
    const float* src = which == 0 ? wq : which == 1 ? wk : which == 2 ? wv : wp;
    Wcat[idx] = f2b(src[r]);
  }
  for (int idx = tid; idx < 512; idx += stride) {
    int which = idx >> 7, r = idx & 127;
    const float* src = which == 0 ? bq : which == 1 ? bk : which == 2 ? bv : bp;
    bcat[idx] = src[r];
  }
  for (int idx = tid; idx < 256 * 128; idx += stride) {
    int o = idx >> 7;
    float s2 = g2[o] * rsqrtf(v2[o] + BN_EPS);
    w2b[idx] = f2b(w2[idx] * s2);
    float s3 = g3[o] * rsqrtf(v3[o] + BN_EPS);
    w3b[idx] = f2b(w3[idx] * s3);
  }
  for (int idx = tid; idx < 256; idx += stride) {
    float s2 = g2[idx] * rsqrtf(v2[idx] + BN_EPS);
    b2e[idx] = b2[idx] - m2[idx] * s2;
    float s3 = g3[idx] * rsqrtf(v3[idx] + BN_EPS);
    b3e[idx] = b3[idx] - m3[idx] * s3;
  }
}

// ---------------------------------------------------------------------------
// prep_xT: transpose x [256][6400] fp32 -> xT [6400][256] bf16.
// grid dim3(8, 100), 256 thr; tile [32 d][64 i] through LDS.
// ---------------------------------------------------------------------------
__global__ void prep_xT(const float* __restrict__ x, u16* __restrict__ xT) {
  __shared__ float tile[32][65];                 // +1 pad: conflict-free both phases
  const int d0 = blockIdx.x * 32;
  const int i0 = blockIdx.y * 64;
  const int t = threadIdx.x;
  {
    const int dr = t >> 3;                       // 0..31
    const int ic = (t & 7) * 8;                  // 0..56
    const float* src = x + (size_t)(d0 + dr) * HW + i0 + ic;
    f32x4 a = *(const f32x4*)src;
    f32x4 b = *(const f32x4*)(src + 4);
#pragma unroll
    for (int e = 0; e < 4; ++e) { tile[dr][ic + e] = a[e]; tile[dr][ic + 4 + e] = b[e]; }
  }
  __syncthreads();
  {
    const int ir = t >> 2;                       // 0..63
    const int dc = (t & 3) * 8;                  // 0..24
    uint4 u;
    u.x = pack2(tile[dc + 0][ir], tile[dc + 1][ir]);
    u.y = pack2(tile[dc + 2][ir], tile[dc + 3][ir]);
    u.z = pack2(tile[dc + 4][ir], tile[dc + 5][ir]);
    u.w = pack2(tile[dc + 6][ir], tile[dc + 7][ir]);
    *(uint4*)(xT + (size_t)(i0 + ir) * 256 + d0 + dc) = u;
  }
}

// ---------------------------------------------------------------------------
// prep_pos: cp = rel_h+rel_w -> LT[i][128+c]; ef -> efT[i][c] and efc[c][i].
// grid <<<80, 256>>> (one block per h row).
// ---------------------------------------------------------------------------
__global__ void prep_pos(const float* __restrict__ rel_h, const float* __restrict__ rel_w,
                         const float* __restrict__ ef_h, const float* __restrict__ ef_w,
                         u16* __restrict__ LT, u16* __restrict__ efT, u16* __restrict__ efc)
{
  const int h = blockIdx.x;
  const int t = threadIdx.x;
  const int c0 = (t & 63) * 2;
  const float rh0 = rel_h[c0 * 80 + h], rh1 = rel_h[(c0 + 1) * 80 + h];
  const float eh0 = ef_h[c0 * 80 + h], eh1 = ef_h[(c0 + 1) * 80 + h];
  for (int wcol = (t >> 6); wcol < 80; wcol += 4) {
    const int i = h * 80 + wcol;
    float rw0 = rel_w[c0 * 80 + wcol], rw1 = rel_w[(c0 + 1) * 80 + wcol];
    float ew0 = ef_w[c0 * 80 + wcol], ew1 = ef_w[(c0 + 1) * 80 + wcol];
    *(unsigned*)&LT[(size_t)i * 256 + 128 + c0] = pack2(rh0 + rw0, rh1 + rw1);
    float e0 = eh0 + ew0, e1 = eh1 + ew1;
    *(unsigned*)&efT[(size_t)i * 128 + c0] = pack2(e0, e1);
    efc[(size_t)c0 * HW + i] = f2b(e0);
    efc[(size_t)(c0 + 1) * HW + i] = f2b(e1);
  }
}

// ---------------------------------------------------------------------------
// gemm_x1: x1T[i][c] = silu(xT[i][:] . w1b[c][:] + b1e[c]).  K=256, N=128.
// grid <<<100, 256>>>; wave w handles rows i0 = blk*64 + w*16.
// ---------------------------------------------------------------------------
__global__ __launch_bounds__(256) void gemm_x1(
    const u16* __restrict__ xT, const u16* __restrict__ w1b,
    const float* __restrict__ b1e, u16* __restrict__ x1T)
{
  __shared__ __align__(16) u16 tr[4][16][136];   // per-wave transpose tile (+8 pad)
  const int t = threadIdx.x, w = t >> 6, lane = t & 63, jl = lane & 15, q = lane >> 4;
  const int i0 = blockIdx.x * 64 + w * 16;
  f32x4 acc[8];
#pragma unroll
  for (int nf = 0; nf < 8; ++nf) acc[nf] = (f32x4){0.f, 0.f, 0.f, 0.f};
#pragma unroll
  for (int ks = 0; ks < 8; ++ks) {
    bf16x8 a = *(const bf16x8*)(xT + (size_t)(i0 + jl) * 256 + ks * 32 + q * 8);
#pragma unroll
    for (int nf = 0; nf < 8; ++nf) {
      bf16x8 b = *(const bf16x8*)(w1b + (size_t)(nf * 16 + jl) * 256 + ks * 32 + q * 8);
      acc[nf] = MFMA(a, b, acc[nf]);
    }
  }
#pragma unroll
  for (int nf = 0; nf < 8; ++nf) {
    const int c = nf * 16 + jl;
    const float bias = b1e[c];
#pragma unroll
    for (int r = 0; r < 4; ++r)
      tr[w][q * 4 + r][c] = f2b(silu_f(acc[nf][r] + bias));
  }
  __syncthreads();
#pragma unroll
  for (int r = 0; r < 16; ++r) {
    unsigned val = *(const unsigned*)&tr[w][r][lane * 2];
    *(unsigned*)(x1T + (size_t)(i0 + r) * 128 + lane * 2) = val;
  }
}

// ---------------------------------------------------------------------------
// gemm_qkvp: [q|k|v|p] = x1T . Wcat^T + bcat, routed into attention layouts.
//   nc=0 (q): LT[i][0:128] and RT[i][128:256]
//   nc=1 (k): RT[i][0:128]
//   nc=2 (v): V[c][i]   (direct C-frag store: 4 consecutive i per lane)
//   nc=3 (p): pT[i][0:128]
// grid dim3(100, 4), 256 thr.
// ---------------------------------------------------------------------------
__global__ __launch_bounds__(256) void gemm_qkvp(
    const u16* __restrict__ x1T, const u16* __restrict__ Wcat, const float* __restrict__ bcat,
    u16* __restrict__ LT, u16* __restrict__ RT, u16* __restrict__ Vv, u16* __restrict__ pT)
{
  __shared__ __align__(16) u16 tr[4][16][136];
  const int t = threadIdx.x, w = t >> 6, lane = t & 63, jl = lane & 15, q = lane >> 4;
  const int i0 = blockIdx.x * 64 + w * 16;
  const int nc = blockIdx.y;
  f32x4 acc[8];
#pragma unroll
  for (int nf = 0; nf < 8; ++nf) acc[nf] = (f32x4){0.f, 0.f, 0.f, 0.f};
#pragma unroll
  for (int ks = 0; ks < 4; ++ks) {
    bf16x8 a = *(const bf16x8*)(x1T + (size_t)(i0 + jl) * 128 + ks * 32 + q * 8);
#pragma unroll
    for (int nf = 0; nf < 8; ++nf) {
      bf16x8 b = *(const bf16x8*)(Wcat + (size_t)(nc * 128 + nf * 16 + jl) * 128 + ks * 32 + q * 8);
      acc[nf] = MFMA(a, b, acc[nf]);
    }
  }
  if (nc == 2) {                                 // V: [c][i] c-major, direct
#pragma unroll
    for (int nf = 0; nf < 8; ++nf) {
      const int c = nf * 16 + jl;
      const float bias = bcat[256 + c];
      uint2 pk;
      pk.x = pack2(acc[nf][0] + bias, acc[nf][1] + bias);
      pk.y = pack2(acc[nf][2] + bias, acc[nf][3] + bias);
      *(uint2*)(Vv + (size_t)c * HW + i0 + q * 4) = pk;
    }
  } else {
#pragma unroll
    for (int nf = 0; nf < 8; ++nf) {
      const int c = nf * 16 + jl;
      const float bias = bcat[nc * 128 + c];
#pragma unroll
      for (int r = 0; r < 4; ++r)
        tr[w][q * 4 + r][c] = f2b(acc[nf][r] + bias);
    }
    __syncthreads();
#pragma unroll
    for (int r = 0; r < 16; ++r) {
      unsigned val = *(const unsigned*)&tr[w][r][lane * 2];
      const size_t row = (size_t)(i0 + r);
      if (nc == 0) {
        *(unsigned*)(LT + row * 256 + lane * 2) = val;
        *(unsigned*)(RT + row * 256 + 128 + lane * 2) = val;
      } else if (nc == 1) {
        *(unsigned*)(RT + row * 256 + lane * 2) = val;
      } else {
        *(unsigned*)(pT + row * 128 + lane * 2) = val;
      }
    }
  }
}

// ---------------------------------------------------------------------------
// Attention (no-max softmax). One block = 128 i-rows x one j-quarter (1600 j).
// 4 waves x 32 rows (2 m-tiles each -> B-frag reuse halves LDS reads).
// R-tile [64][KD] staged in LDS with XOR-8 16B-chunk swizzle (conflict-free
// b128 B-frag reads). V-frags read directly from global (L1 absorbs the 4x
// wave redundancy; keeps LDS at 50 KB < 64 KB static limit).
// P round-trips per-wave LDS [32][72] (pad -> <=2-way conflicts).
// ---------------------------------------------------------------------------
template <int KD>
__device__ __forceinline__ void attn_body(
    const u16* __restrict__ Lt,   // [HW][KD]  i-major (A-side)
    const u16* __restrict__ Rt,   // [HW][KD]  j-major (B-side)
    const u16* __restrict__ Vm,   // [128][HW] c-major (B-side of PV)
    float* __restrict__ Opart,    // [4][HW][128]
    float* __restrict__ lpart,    // [4][HW]
    int it, int jp, u16* Rs, u16* Ps)
{
  const int t = threadIdx.x;
  const int w = t >> 6, lane = t & 63, jl = lane & 15, q = lane >> 4;
  const int i0 = it * 128 + w * 32;
  constexpr int NKS = KD / 32;

  // A (L) fragments: resident in registers across the whole j-loop.
  bf16x8 afr[2][NKS];
#pragma unroll
  for (int mt = 0; mt < 2; ++mt)
#pragma unroll
    for (int ks = 0; ks < NKS; ++ks)
      afr[mt][ks] = *(const bf16x8*)(Lt + (size_t)(i0 + mt * 16 + jl) * KD + ks * 32 + q * 8);

  f32x4 o[2][8];
#pragma unroll
  for (int mt = 0; mt < 2; ++mt)
#pragma unroll
    for (int cf = 0; cf < 8; ++cf) o[mt][cf] = (f32x4){0.f, 0.f, 0.f, 0.f};
  float ls[2][4] = {{0.f, 0.f, 0.f, 0.f}, {0.f, 0.f, 0.f, 0.f}};

  u16* Psw = Ps + w * (32 * 72);
  const int jbase = jp * 1600;

  for (int stp = 0; stp < 25; ++stp) {
    const int jj = jbase + stp * 64;
    __syncthreads();                              // prev iter readers done
    // ---- stage R tile (swizzled): each wave stages rows w*16..w*16+15
    if constexpr (KD == 256) {
#pragma unroll
      for (int cc = 0; cc < 8; ++cc) {
        int jr = w * 16 + cc * 2 + (lane >> 5);   // local row 0..63
        int cp = lane & 31;                       // chunk position in row
        int ch = (cp & ~7) | ((cp ^ jr) & 7);     // source chunk (XOR swizzle)
        u32x4 val = *(const u32x4*)(Rt + (size_t)(jj + jr) * KD + ch * 8);
        *(u32x4*)(Rs + jr * 256 + cp * 8) = val;
      }
    } else {
#pragma unroll
      for (int cc = 0; cc < 4; ++cc) {
        int jr = w * 16 + cc * 4 + (lane >> 4);
        int cp = lane & 15;
        int ch = (cp & ~7) | ((cp ^ jr) & 7);
        u32x4 val = *(const u32x4*)(Rt + (size_t)(jj + jr) * KD + ch * 8);
        *(u32x4*)(Rs + jr * 128 + cp * 8) = val;
      }
    }
    __syncthreads();                              // staging visible to all

    // ---- S tile: [32 i][64 j] per wave, K = KD
    f32x4 s[2][4];
#pragma unroll
    for (int mt = 0; mt < 2; ++mt)
#pragma unroll
      for (int nf = 0; nf < 4; ++nf) s[mt][nf] = (f32x4){0.f, 0.f, 0.f, 0.f};
#pragma unroll
    for (int nf = 0; nf < 4; ++nf) {
      const int row = nf * 16 + jl;
#pragma unroll
      for (int ks = 0; ks < NKS; ++ks) {
        const int ch = (ks * 4 + q) ^ (jl & 7);   // un-swizzle
        bf16x8 b = *(const bf16x8*)(Rs + row * KD + ch * 8);
        s[0][nf] = MFMA(afr[0][ks], b, s[0][nf]);
        s[1][nf] = MFMA(afr[1][ks], b, s[1][nf]);
      }
    }
    // ---- P = exp(S); row sums; write P to per-wave LDS (A-layout source)
#pragma unroll
    for (int mt = 0; mt < 2; ++mt) {
      float rsum[4] = {0.f, 0.f, 0.f, 0.f};
#pragma unroll
      for (int nf = 0; nf < 4; ++nf)
#pragma unroll
        for (int r = 0; r < 4; ++r) {
          float p = __expf(s[mt][nf][r]);
          s[mt][nf][r] = p;
          rsum[r] += p;
        }
#pragma unroll
      for (int d = 1; d < 16; d <<= 1)
#pragma unroll
        for (int r = 0; r < 4; ++r) rsum[r] += __shfl_xor(rsum[r], d);
#pragma unroll
      for (int r = 0; r < 4; ++r) ls[mt][r] += rsum[r];
#pragma unroll
      for (int nf = 0; nf < 4; ++nf)
#pragma unroll
        for (int r = 0; r < 4; ++r)
          Psw[(mt * 16 + q * 4 + r) * 72 + nf * 16 + jl] = f2b(s[mt][nf][r]);
    }
    // ---- O += P . V^T  (V B-frags direct from global; A from Psw)
#pragma unroll
    for (int ks2 = 0; ks2 < 2; ++ks2) {
      bf16x8 a0 = *(const bf16x8*)(Psw + (size_t)jl * 72 + ks2 * 32 + q * 8);
      bf16x8 a1 = *(const bf16x8*)(Psw + (size_t)(16 + jl) * 72 + ks2 * 32 + q * 8);
#pragma unroll
      for (int cf = 0; cf < 8; ++cf) {
        bf16x8 b = *(const bf16x8*)(Vm + (size_t)(cf * 16 + jl) * HW + jj + ks2 * 32 + q * 8);
        o[0][cf] = MFMA(a0, b, o[0][cf]);
        o[1][cf] = MFMA(a1, b, o[1][cf]);
      }
    }
  }
  // ---- epilogue: plain stores to this jp's partial buffer
  float* Ob = Opart + (size_t)jp * HW * 128;
#pragma unroll
  for (int mt = 0; mt < 2; ++mt) {
    const int ib = i0 + mt * 16 + q * 4;
#pragma unroll
    for (int cf = 0; cf < 8; ++cf) {
      const int c = cf * 16 + jl;
#pragma unroll
      for (int r = 0; r < 4; ++r)
        Ob[(size_t)(ib + r) * 128 + c] = o[mt][cf][r];
    }
    if (jl == 0) {
#pragma unroll
      for (int r = 0; r < 4; ++r)
        lpart[(size_t)jp * HW + ib + r] = ls[mt][r];
    }
  }
}

__global__ __launch_bounds__(256, 2) void attn_kernel(
    const u16* __restrict__ LT, const u16* __restrict__ RT, const u16* __restrict__ Vv,
    const u16* __restrict__ pT, const u16* __restrict__ efT, const u16* __restrict__ efc,
    float* __restrict__ Opart, float* __restrict__ lpart)
{
  __shared__ __align__(16) u16 Rs[64 * 256];      // 32 KB (head2 uses half)
  __shared__ __align__(16) u16 Ps[4 * 32 * 72];   // 18 KB  -> total 50 KB
  int b = blockIdx.x;
  if (b < 200) {
    attn_body<256>(LT, RT, Vv, Opart, lpart, b >> 2, b & 3, Rs, Ps);
  } else {
    b -= 200;
    attn_body<128>(pT, efT, efc, Opart + (size_t)4 * HW * 128, lpart + (size_t)4 * HW,
                   b >> 2, b & 3, Rs, Ps);
  }
}

// ---------------------------------------------------------------------------
// combine_k: out?T[i][c] = (sum_p O_p[i][c]) / (sum_p l_p[i]) -> bf16.
// grid <<<1600, 256>>> : 2 heads * 6400 i * 32 float4-groups.
// ---------------------------------------------------------------------------
__global__ void combine_k(const float* __restrict__ Opart, const float* __restrict__ lpart,
                          u16* __restrict__ o1T, u16* __restrict__ o2T)
{
  const int idx = blockIdx.x * 256 + threadIdx.x;
  if (idx >= 2 * HW * 32) return;
  const int hsel = idx >= HW * 32;
  const int rem = idx - hsel * HW * 32;
  const int i = rem >> 5;
  const int c4 = (rem & 31) << 2;
  const float* Ob = Opart + (size_t)hsel * 4 * HW * 128;
  const float* lb = lpart + (size_t)hsel * 4 * HW;
  f32x4 sum = {0.f, 0.f, 0.f, 0.f};
  float lsum = 0.f;
#pragma unroll
  for (int p = 0; p < 4; ++p) {
    sum += *(const f32x4*)(Ob + ((size_t)p * HW + i) * 128 + c4);
    lsum += lb[p * HW + i];
  }
  const float inv = 1.0f / lsum;
  uint2 pk;
  pk.x = pack2(sum[0] * inv, sum[1] * inv);
  pk.y = pack2(sum[2] * inv, sum[3] * inv);
  *(uint2*)((hsel ? o2T : o1T) + (size_t)i * 128 + c4) = pk;
}

// ---------------------------------------------------------------------------
// final_k: out[d][i] = x[d][i] + silu(out1T.w2b + b2e) + silu(out2T.w3b + b3e)
// grid dim3(100, 2), 256 thr. K=128, N=128 per block-column.
// ---------------------------------------------------------------------------
__global__ __launch_bounds__(256) void final_k(
    const u16* __restrict__ o1T, const u16* __restrict__ o2T,
    const u16* __restrict__ w2b, const float* __restrict__ b2e,
    const u16* __restrict__ w3b, const float* __restrict__ b3e,
    const float* __restrict__ x, float* __restrict__ outp)
{
  const int t = threadIdx.x, w = t >> 6, lane = t & 63, jl = lane & 15, q = lane >> 4;
  const int i0 = blockIdx.x * 64 + w * 16;
  const int nc = blockIdx.y;
  f32x4 a1[8], a2[8];
#pragma unroll
  for (int nf = 0; nf < 8; ++nf) {
    a1[nf] = (f32x4){0.f, 0.f, 0.f, 0.f};
    a2[nf] = (f32x4){0.f, 0.f, 0.f, 0.f};
  }
#pragma unroll
  for (int ks = 0; ks < 4; ++ks) {
    bf16x8 fa1 = *(const bf16x8*)(o1T + (size_t)(i0 + jl) * 128 + ks * 32 + q * 8);
    bf16x8 fa2 = *(const bf16x8*)(o2T + (size_t)(i0 + jl) * 128 + ks * 32 + q * 8);
#pragma unroll
    for (int nf = 0; nf < 8; ++nf) {
      bf16x8 b2f = *(const bf16x8*)(w2b + (size_t)(nc * 128 + nf * 16 + jl) * 128 + ks * 32 + q * 8);
      bf16x8 b3f = *(const bf16x8*)(w3b + (size_t)(nc * 128 + nf * 16 + jl) * 128 + ks * 32 + q * 8);
      a1[nf] = MFMA(fa1, b2f, a1[nf]);
      a2[nf] = MFMA(fa2, b3f, a2[nf]);
    }
  }
#pragma unroll
  for (int nf = 0; nf < 8; ++nf) {
    const int d = nc * 128 + nf * 16 + jl;
    const float bb2 = b2e[d], bb3 = b3e[d];
    const size_t base = (size_t)d * HW + i0 + q * 4;
    f32x4 xv = *(const f32x4*)(x + base);
    f32x4 rv;
#pragma unroll
    for (int r = 0; r < 4; ++r)
      rv[r] = xv[r] + silu_f(a1[nf][r] + bb2) + silu_f(a2[nf][r] + bb3);
    *(f32x4*)(outp + base) = rv;
  }
}

// ---------------------------------------------------------------------------
extern "C" void kernel_launch(void* const* d_in, const int* in_sizes, int n_in,
                              void* d_out, int out_size, void* d_ws, size_t ws_size,
                              hipStream_t stream)
{
  (void)in_sizes; (void)n_in; (void)out_size; (void)ws_size;
  const float* x   = (const float*)d_in[0];
  const float* w1  = (const float*)d_in[1];
  const float* g1  = (const float*)d_in[2];
  const float* b1  = (const float*)d_in[3];
  const float* m1  = (const float*)d_in[4];
  const float* v1  = (const float*)d_in[5];
  const float* w2  = (const float*)d_in[6];
  const float* g2  = (const float*)d_in[7];
  const float* b2  = (const float*)d_in[8];
  const float* m2  = (const float*)d_in[9];
  const float* v2  = (const float*)d_in[10];
  const float* w3  = (const float*)d_in[11];
  const float* g3  = (const float*)d_in[12];
  const float* b3  = (const float*)d_in[13];
  const float* m3  = (const float*)d_in[14];
  const float* v3  = (const float*)d_in[15];
  const float* wq  = (const float*)d_in[16];
  const float* bq  = (const float*)d_in[17];
  const float* wk  = (const float*)d_in[18];
  const float* bk  = (const float*)d_in[19];
  const float* wv  = (const float*)d_in[20];
  const float* bv  = (const float*)d_in[21];
  const float* wp  = (const float*)d_in[22];
  const float* bp  = (const float*)d_in[23];
  const float* rel_h = (const float*)d_in[24];
  const float* rel_w = (const float*)d_in[25];
  const float* ef_h  = (const float*)d_in[26];
  const float* ef_w  = (const float*)d_in[27];
  float* outp = (float*)d_out;

  char* ws = (char*)d_ws;
  size_t off = 0;
  auto alloc = [&](size_t bytes) -> void* {
    void* p = ws + off;
    off += (bytes + 511) & ~(size_t)511;
    return p;
  };
  u16* xT    = (u16*)alloc((size_t)HW * 256 * 2);
  u16* x1T   = (u16*)alloc((size_t)HW * 128 * 2);
  u16* LT    = (u16*)alloc((size_t)HW * 256 * 2);
  u16* RT    = (u16*)alloc((size_t)HW * 256 * 2);
  u16* pT    = (u16*)alloc((size_t)HW * 128 * 2);
  u16* efT   = (u16*)alloc((size_t)HW * 128 * 2);
  u16* efc   = (u16*)alloc((size_t)HW * 128 * 2);
  u16* Vv    = (u16*)alloc((size_t)HW * 128 * 2);
  u16* o1T   = (u16*)alloc((size_t)HW * 128 * 2);
  u16* o2T   = (u16*)alloc((size_t)HW * 128 * 2);
  float* Opart = (float*)alloc((size_t)2 * 4 * HW * 128 * 4);  // 26.2 MB
  float* lpart = (float*)alloc((size_t)2 * 4 * HW * 4);
  u16* w1b   = (u16*)alloc(128 * 256 * 2);
  float* b1e = (float*)alloc(128 * 4);
  u16* Wcat  = (u16*)alloc(512 * 128 * 2);
  float* bcat = (float*)alloc(512 * 4);
  u16* w2b   = (u16*)alloc(256 * 128 * 2);
  float* b2e = (float*)alloc(256 * 4);
  u16* w3b   = (u16*)alloc(256 * 128 * 2);
  float* b3e = (float*)alloc(256 * 4);

  prep_weights<<<64, 256, 0, stream>>>(w1, g1, b1, m1, v1, w2, g2, b2, m2, v2,
                                       w3, g3, b3, m3, v3, wq, bq, wk, bk, wv, bv, wp, bp,
                                       w1b, b1e, Wcat, bcat, w2b, b2e, w3b, b3e);
  prep_xT<<<dim3(8, 100), 256, 0, stream>>>(x, xT);
  prep_pos<<<80, 256, 0, stream>>>(rel_h, rel_w, ef_h, ef_w, LT, efT, efc);
  gemm_x1<<<100, 256, 0, stream>>>(xT, w1b, b1e, x1T);
  gemm_qkvp<<<dim3(100, 4), 256, 0, stream>>>(x1T, Wcat, bcat, LT, RT, Vv, pT);
  attn_kernel<<<400, 256, 0, stream>>>(LT, RT, Vv, pT, efT, efc, Opart, lpart);
  combine_k<<<1600, 256, 0, stream>>>(Opart, lpart, o1T, o2T);
  final_k<<<dim3(100, 2), 256, 0, stream>>>(o1T, o2T, w2b, b2e, w3b, b3e, x, outp);
}